// Round 8
// baseline (519.877 us; speedup 1.0000x reference)
//
#include <hip/hip_runtime.h>

// Problem constants (from reference)
constexpr int COLS    = 8;
constexpr int BATCH   = 8192;
constexpr int D       = 128;
constexpr int NUM_EMB = 12;
constexpr int NPAIRS  = 28;

typedef float floatx4 __attribute__((ext_vector_type(4)));

__device__ __forceinline__ float dot4(const floatx4 a, const floatx4 b) {
    return fmaf(a.x, b.x, fmaf(a.y, b.y, fmaf(a.z, b.z, a.w * b.w)));
}

__device__ __forceinline__ floatx4 ld4(const float* p) {
    return *reinterpret_cast<const floatx4*>(p);
}

__device__ __forceinline__ void st4(float* p, const floatx4 v) {
    *reinterpret_cast<floatx4*>(p) = v;
}

__device__ __forceinline__ float softplus01(float x) {
    return 0.01f * ((x > 15.0f) ? x : log1pf(expf(x)));
}

// Block = 256 threads = 4 waves; each 32-lane half-wave owns one batch row.
// Weights in LDS ([28][4][128] f32, zeroed B rows for non-cat). The k-loop is
// fully unrolled with a sched_barrier(0) fence per iteration: the scheduler
// cannot hoist loads across iterations, so VGPR pressure stays at the designed
// ~140 (no spills). Depth-2 manual noise prefetch -> counted vmcnt, never 0.
__global__ void dsnas_kernel(
    const int*   __restrict__ features,   // [COLS, BATCH]
    const float* __restrict__ emb_mean,   // [COLS, NUM_EMB, D]
    const float* __restrict__ emb_std,    // [COLS, NUM_EMB, D]
    const float* __restrict__ W_nc,       // [NPAIRS, 4, 2, D]
    const float* __restrict__ W_cat,      // [NPAIRS, 2, 2*D]
    const float* __restrict__ log_alpha,  // [NPAIRS, 5]
    const float* __restrict__ noise,      // [NPAIRS, 2, BATCH, D]
    float*       __restrict__ out)        // [BATCH, 2]
{
    // Per pair k, 4 rows of 128 floats: [A0 | B0 | A1 | B1].
    //  cat (s==4): copy of W_cat[k] (512 floats) -> contrib dot(p,A)+dot(q,B)
    //  non-cat:    [wnc_row0 | 0 | wnc_row1 | 0] -> contrib dot(c,A)+dot(q,0)
    __shared__ float wlds[NPAIRS * 512];
    __shared__ int   pos_s[NPAIRS];

    const int tid = threadIdx.x;

    // Hard top-1 routing per pair (argmax over 5, first-max wins)
    if (tid < NPAIRS) {
        const float* la = log_alpha + tid * 5;
        float best = la[0];
        int   bi   = 0;
        #pragma unroll
        for (int t = 1; t < 5; ++t) {
            float v = la[t];
            if (v > best) { best = v; bi = t; }
        }
        pos_s[tid] = bi;
    }
    __syncthreads();

    // ---- Stage selected weights into LDS (256 threads cooperatively) ----
    // 28 pairs * 128 float4 slots = 3584; 14 per thread.
    #pragma unroll
    for (int r = 0; r < 14; ++r) {
        const int idx = tid + r * 256;     // float4 slot id
        const int k   = idx >> 7;          // pair (128 f4 per pair)
        const int f   = idx & 127;         // f4 within pair
        const int row = f >> 5;            // 0..3 (32 f4 per row)
        const int c4  = f & 31;            // f4 within row
        const int s   = pos_s[k];
        floatx4 v = {0.0f, 0.0f, 0.0f, 0.0f};
        if (s == 4) {
            v = ld4(W_cat + (size_t)k * 512 + f * 4);
        } else if ((row & 1) == 0) {
            v = ld4(W_nc + (size_t)(k * 4 + s) * 256 + (row >> 1) * 128 + c4 * 4);
        }
        st4(wlds + k * 512 + f * 4, v);
    }

    // Loop-invariant routing masks, hoisted to SGPRs via readfirstlane.
    unsigned cat_m = 0;
    unsigned long long op_m = 0;
    #pragma unroll
    for (int k = 0; k < NPAIRS; ++k) {
        const int s = pos_s[k];
        cat_m |= (unsigned)(s == 4 ? 1 : 0) << k;
        op_m  |= (unsigned long long)(s & 3) << (2 * k);
    }
    const unsigned cat_mask = __builtin_amdgcn_readfirstlane(cat_m);
    const unsigned ops_lo   = __builtin_amdgcn_readfirstlane((unsigned)op_m);
    const unsigned ops_hi   = __builtin_amdgcn_readfirstlane((unsigned)(op_m >> 32));
    __syncthreads();

    const int b    = blockIdx.x * 8 + (tid >> 5);  // one batch row per half-wave
    const int lane = tid & 31;
    const int d0   = lane * 4;                     // 4 consecutive dims per lane

    // Per-column mean + 0.01*softplus(std) for this row's 4 dims, in VGPRs.
    floatx4 Mv[COLS], Sv[COLS];
    #pragma unroll
    for (int i = 0; i < COLS; ++i) {
        const int fi = features[i * BATCH + b];
        const floatx4 m = ld4(emb_mean + ((size_t)(i * NUM_EMB + fi)) * D + d0);
        const floatx4 s = ld4(emb_std  + ((size_t)(i * NUM_EMB + fi)) * D + d0);
        Mv[i] = m;
        floatx4 sp;
        sp.x = softplus01(s.x);
        sp.y = softplus01(s.y);
        sp.z = softplus01(s.z);
        sp.w = softplus01(s.w);
        Sv[i] = sp;
    }

    constexpr int PI[NPAIRS] = {0,0,0,0,0,0,0, 1,1,1,1,1,1, 2,2,2,2,2, 3,3,3,3, 4,4,4, 5,5, 6};
    constexpr int PJ[NPAIRS] = {1,2,3,4,5,6,7, 2,3,4,5,6,7, 3,4,5,6,7, 4,5,6,7, 5,6,7, 6,7, 7};

    const float* nrow = noise + (size_t)b * D + d0;
    constexpr size_t KSTRIDE = (size_t)2 * BATCH * D;  // between pairs k
    constexpr size_t HSTRIDE = (size_t)BATCH * D;      // between halves

    // Depth-2 rotating noise buffers; all indices compile-time after unroll.
    floatx4 nb0[3], nb1[3];
    nb0[0] = ld4(nrow);
    nb1[0] = ld4(nrow + HSTRIDE);
    nb0[1] = ld4(nrow + KSTRIDE);
    nb1[1] = ld4(nrow + KSTRIDE + HSTRIDE);

    float acc0 = 0.0f, acc1 = 0.0f;

    #pragma unroll
    for (int k = 0; k < NPAIRS; ++k) {
        const int cur = k % 3;
        const int pf  = (k + 2) % 3;

        // Issue noise for pair k+2 (2 VMEM). Consuming pair k below leaves
        // 4 loads outstanding -> compiler emits vmcnt(4), never a full drain.
        if (k + 2 < NPAIRS) {
            nb0[pf] = ld4(nrow + (size_t)(k + 2) * KSTRIDE);
            nb1[pf] = ld4(nrow + (size_t)(k + 2) * KSTRIDE + HSTRIDE);
        }

        // Weights from LDS (half-waves read identical addresses: broadcast)
        const float* wk = wlds + k * 512 + d0;
        const floatx4 A0 = ld4(wk);
        const floatx4 B0 = ld4(wk + 128);
        const floatx4 A1 = ld4(wk + 256);
        const floatx4 B1 = ld4(wk + 384);

        // Reparameterize (noise loaded 2 iterations ago)
        const int i = PI[k];
        const int j = PJ[k];
        const floatx4 n0 = nb0[cur];
        const floatx4 n1 = nb1[cur];
        floatx4 p, q;
        p.x = fmaf(Sv[i].x, n0.x, Mv[i].x);
        p.y = fmaf(Sv[i].y, n0.y, Mv[i].y);
        p.z = fmaf(Sv[i].z, n0.z, Mv[i].z);
        p.w = fmaf(Sv[i].w, n0.w, Mv[i].w);
        q.x = fmaf(Sv[j].x, n1.x, Mv[j].x);
        q.y = fmaf(Sv[j].y, n1.y, Mv[j].y);
        q.z = fmaf(Sv[j].z, n1.z, Mv[j].z);
        q.w = fmaf(Sv[j].w, n1.w, Mv[j].w);

        // Branchless combine via SGPR masks (k literal -> SALU bit tests)
        const bool s4 = (cat_mask >> k) & 1u;
        const int  op = (int)((k < 16 ? (ops_lo >> (2 * k))
                                      : (ops_hi >> (2 * (k - 16)))) & 3u);
        const bool lo = op < 2;       // {add,mul} vs {max,min}
        const bool ev = (op & 1) == 0;
        floatx4 c, u;
        c.x = lo ? (ev ? p.x + q.x : p.x * q.x) : (ev ? fmaxf(p.x, q.x) : fminf(p.x, q.x));
        c.y = lo ? (ev ? p.y + q.y : p.y * q.y) : (ev ? fmaxf(p.y, q.y) : fminf(p.y, q.y));
        c.z = lo ? (ev ? p.z + q.z : p.z * q.z) : (ev ? fmaxf(p.z, q.z) : fminf(p.z, q.z));
        c.w = lo ? (ev ? p.w + q.w : p.w * q.w) : (ev ? fmaxf(p.w, q.w) : fminf(p.w, q.w));
        u.x = s4 ? p.x : c.x;
        u.y = s4 ? p.y : c.y;
        u.z = s4 ? p.z : c.z;
        u.w = s4 ? p.w : c.w;

        // B rows are zero for non-cat, so q's contribution vanishes exactly.
        acc0 += dot4(u, A0) + dot4(q, B0);
        acc1 += dot4(u, A1) + dot4(q, B1);

        // Fence: no instruction may be hoisted across iterations.
        __builtin_amdgcn_sched_barrier(0);
    }

    // Reduce across the 32 lanes of this half-wave
    #pragma unroll
    for (int m = 16; m >= 1; m >>= 1) {
        acc0 += __shfl_xor(acc0, m, 64);
        acc1 += __shfl_xor(acc1, m, 64);
    }

    if (lane == 0) {
        out[b * 2 + 0] = acc0;
        out[b * 2 + 1] = acc1;
    }
}

extern "C" void kernel_launch(void* const* d_in, const int* in_sizes, int n_in,
                              void* d_out, int out_size, void* d_ws, size_t ws_size,
                              hipStream_t stream) {
    const int*   features  = (const int*)  d_in[0];
    const float* emb_mean  = (const float*)d_in[1];
    const float* emb_std   = (const float*)d_in[2];
    const float* W_nc      = (const float*)d_in[3];
    const float* W_cat     = (const float*)d_in[4];
    const float* log_alpha = (const float*)d_in[5];
    const float* noise     = (const float*)d_in[6];
    float*       out       = (float*)d_out;

    dim3 grid(BATCH / 8);   // 1024 blocks
    dim3 block(256);        // 4 waves, 8 batch rows/block
    dsnas_kernel<<<grid, block, 0, stream>>>(features, emb_mean, emb_std,
                                             W_nc, W_cat, log_alpha, noise, out);
}

// Round 9
// 431.819 us; speedup vs baseline: 1.2039x; 1.2039x over previous
//
#include <hip/hip_runtime.h>
#include <utility>

// Problem constants (from reference)
constexpr int COLS    = 8;
constexpr int BATCH   = 8192;
constexpr int D       = 128;
constexpr int NUM_EMB = 12;
constexpr int NPAIRS  = 28;

typedef float floatx4 __attribute__((ext_vector_type(4)));

// Pair tables as constexpr functions: indexed ONLY with template parameters,
// so folding is guaranteed by language semantics (not by the unroller).
constexpr int PI_f(int k) {
    constexpr int a[NPAIRS] = {0,0,0,0,0,0,0, 1,1,1,1,1,1, 2,2,2,2,2, 3,3,3,3, 4,4,4, 5,5, 6};
    return a[k];
}
constexpr int PJ_f(int k) {
    constexpr int a[NPAIRS] = {1,2,3,4,5,6,7, 2,3,4,5,6,7, 3,4,5,6,7, 4,5,6,7, 5,6,7, 6,7, 7};
    return a[k];
}

__device__ __forceinline__ floatx4 ld4(const float* p) {
    return *reinterpret_cast<const floatx4*>(p);
}
__device__ __forceinline__ void st4(float* p, floatx4 v) {
    *reinterpret_cast<floatx4*>(p) = v;
}
__device__ __forceinline__ float softplus01(float x) {
    return 0.01f * ((x > 15.0f) ? x : log1pf(expf(x)));
}
__device__ __forceinline__ float dot4(floatx4 a, floatx4 b) {
    return fmaf(a.x, b.x, fmaf(a.y, b.y, fmaf(a.z, b.z, a.w * b.w)));
}
__device__ __forceinline__ floatx4 vmax4(floatx4 a, floatx4 b) {
    floatx4 r; r.x=fmaxf(a.x,b.x); r.y=fmaxf(a.y,b.y); r.z=fmaxf(a.z,b.z); r.w=fmaxf(a.w,b.w); return r;
}
__device__ __forceinline__ floatx4 vmin4(floatx4 a, floatx4 b) {
    floatx4 r; r.x=fminf(a.x,b.x); r.y=fminf(a.y,b.y); r.z=fminf(a.z,b.z); r.w=fminf(a.w,b.w); return r;
}

// One pair's contribution. Every array index is template-constant.
template<int K>
__device__ __forceinline__ void pair_step(const float* __restrict__ nrow,
                                          const float* __restrict__ wbase,
                                          const floatx4 (&Mv)[COLS],
                                          const floatx4 (&Sv)[COLS],
                                          unsigned cat_mask, unsigned ops_lo, unsigned ops_hi,
                                          float& acc0, float& acc1)
{
    constexpr int    i    = PI_f(K);
    constexpr int    j    = PJ_f(K);
    constexpr size_t KOFF = (size_t)K * 2 * BATCH * D;
    constexpr size_t HOFF = (size_t)BATCH * D;

    // The only VMEM in the main phase: this pair's two noise vectors.
    const floatx4 n0 = ld4(nrow + KOFF);
    const floatx4 n1 = ld4(nrow + KOFF + HOFF);

    // Weights from LDS: [A0 | B0 | A1 | B1] rows of 128 floats.
    const float* wk = wbase + K * 512;
    const floatx4 A0 = ld4(wk);
    const floatx4 B0 = ld4(wk + 128);
    const floatx4 A1 = ld4(wk + 256);
    const floatx4 B1 = ld4(wk + 384);

    const floatx4 p = Mv[i] + Sv[i] * n0;   // Sv is pre-scaled by 0.01
    const floatx4 q = Mv[j] + Sv[j] * n1;

    // Routing via SGPR masks; K is a literal -> scalar bit tests.
    const bool s4 = (cat_mask >> K) & 1u;
    const int  op = (int)(((K < 16) ? (ops_lo >> (2 * K)) : (ops_hi >> (2 * (K - 16)))) & 3u);
    const bool lo = op < 2;          // {add,mul} vs {max,min}
    const bool ev = (op & 1) == 0;

    const floatx4 c = lo ? (ev ? p + q : p * q) : (ev ? vmax4(p, q) : vmin4(p, q));
    const floatx4 u = s4 ? p : c;

    // B rows are zero for non-cat pairs, so q's term vanishes exactly there.
    acc0 += dot4(u, A0) + dot4(q, B0);
    acc1 += dot4(u, A1) + dot4(q, B1);
}

template<int... Ks>
__device__ __forceinline__ void run_all(std::integer_sequence<int, Ks...>,
                                        const float* __restrict__ nrow,
                                        const float* __restrict__ wbase,
                                        const floatx4 (&Mv)[COLS],
                                        const floatx4 (&Sv)[COLS],
                                        unsigned cm, unsigned ol, unsigned oh,
                                        float& a0, float& a1)
{
    (pair_step<Ks>(nrow, wbase, Mv, Sv, cm, ol, oh, a0, a1), ...);
}

// Column init, also template-unrolled (no unroller dependence).
template<int I>
__device__ __forceinline__ void init_col(const int* __restrict__ features,
                                         const float* __restrict__ emb_mean,
                                         const float* __restrict__ emb_std,
                                         int b, int d0,
                                         floatx4 (&Mv)[COLS], floatx4 (&Sv)[COLS])
{
    const int fi = features[I * BATCH + b];
    Mv[I] = ld4(emb_mean + ((size_t)(I * NUM_EMB + fi)) * D + d0);
    const floatx4 s = ld4(emb_std + ((size_t)(I * NUM_EMB + fi)) * D + d0);
    floatx4 sp;
    sp.x = softplus01(s.x);
    sp.y = softplus01(s.y);
    sp.z = softplus01(s.z);
    sp.w = softplus01(s.w);
    Sv[I] = sp;
}

template<int... Is>
__device__ __forceinline__ void init_cols(std::integer_sequence<int, Is...>,
                                          const int* __restrict__ features,
                                          const float* __restrict__ emb_mean,
                                          const float* __restrict__ emb_std,
                                          int b, int d0,
                                          floatx4 (&Mv)[COLS], floatx4 (&Sv)[COLS])
{
    (init_col<Is>(features, emb_mean, emb_std, b, d0, Mv, Sv), ...);
}

// Block = 256 threads = 4 waves; each 32-lane half-wave owns one batch row.
__global__ void dsnas_kernel(
    const int*   __restrict__ features,   // [COLS, BATCH]
    const float* __restrict__ emb_mean,   // [COLS, NUM_EMB, D]
    const float* __restrict__ emb_std,    // [COLS, NUM_EMB, D]
    const float* __restrict__ W_nc,       // [NPAIRS, 4, 2, D]
    const float* __restrict__ W_cat,      // [NPAIRS, 2, 2*D]
    const float* __restrict__ log_alpha,  // [NPAIRS, 5]
    const float* __restrict__ noise,      // [NPAIRS, 2, BATCH, D]
    float*       __restrict__ out)        // [BATCH, 2]
{
    // Per pair k: [A0 | B0 | A1 | B1], 128 floats each.
    //  cat (s==4): copy of W_cat[k] -> contrib dot(p,A)+dot(q,B)
    //  non-cat:    [w_row0 | 0 | w_row1 | 0] -> contrib dot(c,A)+dot(q,0)
    __shared__ float wlds[NPAIRS * 512];
    __shared__ int   pos_s[NPAIRS];

    const int tid = threadIdx.x;

    // Hard top-1 routing per pair (argmax over 5, first-max wins)
    if (tid < NPAIRS) {
        const float* la = log_alpha + tid * 5;
        float best = la[0];
        int   bi   = 0;
        #pragma unroll
        for (int t = 1; t < 5; ++t) {
            float v = la[t];
            if (v > best) { best = v; bi = t; }
        }
        pos_s[tid] = bi;
    }
    __syncthreads();

    // ---- Stage selected weights into LDS (256 threads cooperatively) ----
    // 28 pairs * 128 float4 slots = 3584; 14 per thread. (LDS writes -> memory,
    // runtime indexing here is fine.)
    #pragma unroll
    for (int r = 0; r < 14; ++r) {
        const int idx = tid + r * 256;     // float4 slot id
        const int k   = idx >> 7;          // pair (128 f4 per pair)
        const int f   = idx & 127;         // f4 within pair
        const int row = f >> 5;            // 0..3 (32 f4 per row)
        const int c4  = f & 31;            // f4 within row
        const int s   = pos_s[k];
        floatx4 v = {0.0f, 0.0f, 0.0f, 0.0f};
        if (s == 4) {
            v = ld4(W_cat + (size_t)k * 512 + f * 4);
        } else if ((row & 1) == 0) {
            v = ld4(W_nc + (size_t)(k * 4 + s) * 256 + (row >> 1) * 128 + c4 * 4);
        }
        st4(wlds + k * 512 + f * 4, v);
    }

    // Loop-invariant routing masks -> SGPRs.
    unsigned cat_m = 0;
    unsigned op_lo = 0, op_hi = 0;
    #pragma unroll
    for (int k = 0; k < NPAIRS; ++k) {
        const int s = pos_s[k];
        cat_m |= (unsigned)(s == 4 ? 1 : 0) << k;
        if (k < 16) op_lo |= (unsigned)(s & 3) << (2 * k);
        else        op_hi |= (unsigned)(s & 3) << (2 * (k - 16));
    }
    const unsigned cat_mask = __builtin_amdgcn_readfirstlane(cat_m);
    const unsigned ops_lo   = __builtin_amdgcn_readfirstlane(op_lo);
    const unsigned ops_hi   = __builtin_amdgcn_readfirstlane(op_hi);
    __syncthreads();

    const int b    = blockIdx.x * 8 + (tid >> 5);  // one batch row per half-wave
    const int lane = tid & 31;
    const int d0   = lane * 4;                     // 4 consecutive dims per lane

    floatx4 Mv[COLS], Sv[COLS];
    init_cols(std::make_integer_sequence<int, COLS>{},
              features, emb_mean, emb_std, b, d0, Mv, Sv);

    const float* nrow  = noise + (size_t)b * D + d0;
    const float* wbase = wlds + d0;

    float acc0 = 0.0f, acc1 = 0.0f;
    run_all(std::make_integer_sequence<int, NPAIRS>{},
            nrow, wbase, Mv, Sv, cat_mask, ops_lo, ops_hi, acc0, acc1);

    // Reduce across the 32 lanes of this half-wave
    #pragma unroll
    for (int m = 16; m >= 1; m >>= 1) {
        acc0 += __shfl_xor(acc0, m, 64);
        acc1 += __shfl_xor(acc1, m, 64);
    }

    if (lane == 0) {
        out[b * 2 + 0] = acc0;
        out[b * 2 + 1] = acc1;
    }
}

extern "C" void kernel_launch(void* const* d_in, const int* in_sizes, int n_in,
                              void* d_out, int out_size, void* d_ws, size_t ws_size,
                              hipStream_t stream) {
    const int*   features  = (const int*)  d_in[0];
    const float* emb_mean  = (const float*)d_in[1];
    const float* emb_std   = (const float*)d_in[2];
    const float* W_nc      = (const float*)d_in[3];
    const float* W_cat     = (const float*)d_in[4];
    const float* log_alpha = (const float*)d_in[5];
    const float* noise     = (const float*)d_in[6];
    float*       out       = (float*)d_out;

    dim3 grid(BATCH / 8);   // 1024 blocks
    dim3 block(256);        // 4 waves, 8 batch rows/block
    dsnas_kernel<<<grid, block, 0, stream>>>(features, emb_mean, emb_std,
                                             W_nc, W_cat, log_alpha, noise, out);
}

// Round 10
// 54.741 us; speedup vs baseline: 9.4970x; 7.8884x over previous
//
#include <hip/hip_runtime.h>

// Problem constants (from reference)
constexpr int COLS    = 8;
constexpr int BATCH   = 8192;
constexpr int D       = 128;
constexpr int NUM_EMB = 12;
constexpr int NPAIRS  = 28;

typedef float floatx4 __attribute__((ext_vector_type(4)));

__device__ __forceinline__ floatx4 ld4(const float* p) {
    return *reinterpret_cast<const floatx4*>(p);
}
__device__ __forceinline__ void st4(float* p, floatx4 v) {
    *reinterpret_cast<floatx4*>(p) = v;
}
__device__ __forceinline__ float softplus01(float x) {
    return 0.01f * ((x > 15.0f) ? x : log1pf(expf(x)));
}
__device__ __forceinline__ float dot4(floatx4 a, floatx4 b) {
    return fmaf(a.x, b.x, fmaf(a.y, b.y, fmaf(a.z, b.z, a.w * b.w)));
}

// Block = 512 threads = 8 waves; each 32-lane half-wave owns one batch row
// (16 rows/block, grid = 512). LDS weights (57 KB) -> 2 blocks/CU; the
// (512,4) bound caps VGPR at 128 so both blocks fit: 16 waves/CU.
// Loop body keeps R2's branchy shape (branches bound scheduler hoisting ->
// no pressure blowup / no spills) but weights come from LDS, so the ONLY
// VMEM in the k-loop is the depth-1 prefetched noise stream.
__global__ __launch_bounds__(512, 4) void dsnas_kernel(
    const int*   __restrict__ features,   // [COLS, BATCH]
    const float* __restrict__ emb_mean,   // [COLS, NUM_EMB, D]
    const float* __restrict__ emb_std,    // [COLS, NUM_EMB, D]
    const float* __restrict__ W_nc,       // [NPAIRS, 4, 2, D]
    const float* __restrict__ W_cat,      // [NPAIRS, 2, 2*D]
    const float* __restrict__ log_alpha,  // [NPAIRS, 5]
    const float* __restrict__ noise,      // [NPAIRS, 2, BATCH, D]
    float*       __restrict__ out)        // [BATCH, 2]
{
    // Per pair k: 512 floats.
    //  cat (s==4): raw copy of W_cat[k]  -> [a0|b0] at 0..255, [a1|b1] at 256..511
    //  non-cat:    W_nc[k][s] row0 at 0..127, row1 at 256..383 (rest zero, unread)
    __shared__ float wlds[NPAIRS * 512];
    __shared__ int   pos_s[NPAIRS];

    const int tid = threadIdx.x;

    // Hard top-1 routing per pair (argmax over 5, first-max wins)
    if (tid < NPAIRS) {
        const float* la = log_alpha + tid * 5;
        float best = la[0];
        int   bi   = 0;
        #pragma unroll
        for (int t = 1; t < 5; ++t) {
            float v = la[t];
            if (v > best) { best = v; bi = t; }
        }
        pos_s[tid] = bi;
    }
    __syncthreads();

    // ---- Stage selected weights into LDS (512 threads cooperatively) ----
    // 28 pairs * 128 float4 slots = 3584; 7 per thread.
    #pragma unroll
    for (int r = 0; r < 7; ++r) {
        const int idx = tid + r * 512;     // float4 slot id
        const int k   = idx >> 7;          // pair (128 f4 per pair)
        const int f   = idx & 127;         // f4 within pair
        const int row = f >> 5;            // 0..3 (32 f4 per row)
        const int c4  = f & 31;            // f4 within row
        const int s   = pos_s[k];
        floatx4 v = {0.0f, 0.0f, 0.0f, 0.0f};
        if (s == 4) {
            v = ld4(W_cat + (size_t)k * 512 + f * 4);
        } else if ((row & 1) == 0) {
            v = ld4(W_nc + (size_t)(k * 4 + s) * 256 + (row >> 1) * 128 + c4 * 4);
        }
        st4(wlds + k * 512 + f * 4, v);
    }
    __syncthreads();

    const int b    = blockIdx.x * 16 + (tid >> 5); // one batch row per half-wave
    const int lane = tid & 31;
    const int d0   = lane * 4;                     // 4 consecutive dims per lane

    // Per-column mean + 0.01*softplus(std) for this row's 4 dims, in VGPRs.
    floatx4 Mv[COLS], Sv[COLS];
    #pragma unroll
    for (int i = 0; i < COLS; ++i) {
        const int fi = features[i * BATCH + b];
        Mv[i] = ld4(emb_mean + ((size_t)(i * NUM_EMB + fi)) * D + d0);
        const floatx4 s = ld4(emb_std + ((size_t)(i * NUM_EMB + fi)) * D + d0);
        floatx4 sp;
        sp.x = softplus01(s.x);
        sp.y = softplus01(s.y);
        sp.z = softplus01(s.z);
        sp.w = softplus01(s.w);
        Sv[i] = sp;
    }

    constexpr int PI[NPAIRS] = {0,0,0,0,0,0,0, 1,1,1,1,1,1, 2,2,2,2,2, 3,3,3,3, 4,4,4, 5,5, 6};
    constexpr int PJ[NPAIRS] = {1,2,3,4,5,6,7, 2,3,4,5,6,7, 3,4,5,6,7, 4,5,6,7, 5,6,7, 6,7, 7};

    const float* nrow = noise + (size_t)b * D + d0;
    constexpr size_t KSTRIDE = (size_t)2 * BATCH * D;  // between pairs k
    constexpr size_t HSTRIDE = (size_t)BATCH * D;      // between halves

    // Depth-1 double buffer exactly as R2 (k&1 indices, full unroll).
    floatx4 nb0[2], nb1[2];
    nb0[0] = ld4(nrow);
    nb1[0] = ld4(nrow + HSTRIDE);

    float acc0 = 0.0f, acc1 = 0.0f;

    #pragma unroll
    for (int k = 0; k < NPAIRS; ++k) {
        const int buf = k & 1;
        const int nxt = buf ^ 1;

        // Prefetch next pair's noise: the ONLY VMEM in this loop.
        if (k + 1 < NPAIRS) {
            nb0[nxt] = ld4(nrow + (size_t)(k + 1) * KSTRIDE);
            nb1[nxt] = ld4(nrow + (size_t)(k + 1) * KSTRIDE + HSTRIDE);
        }

        // Reparameterize (noise issued one iteration ago)
        const int i = PI[k];
        const int j = PJ[k];
        const floatx4 n0 = nb0[buf];
        const floatx4 n1 = nb1[buf];
        const floatx4 p = Mv[i] + Sv[i] * n0;   // Sv pre-scaled by 0.01
        const floatx4 q = Mv[j] + Sv[j] * n1;

        // R2-style wave-uniform branch; weights from LDS only.
        const int    s  = __builtin_amdgcn_readfirstlane(pos_s[k]);
        const float* wk = wlds + k * 512 + d0;

        if (s == 4) {
            const floatx4 A0 = ld4(wk);
            const floatx4 B0 = ld4(wk + 128);
            const floatx4 A1 = ld4(wk + 256);
            const floatx4 B1 = ld4(wk + 384);
            acc0 += dot4(p, A0) + dot4(q, B0);
            acc1 += dot4(p, A1) + dot4(q, B1);
        } else {
            floatx4 c;
            if (s == 0) {
                c = p + q;
            } else if (s == 1) {
                c = p * q;
            } else if (s == 2) {
                c.x = fmaxf(p.x, q.x); c.y = fmaxf(p.y, q.y);
                c.z = fmaxf(p.z, q.z); c.w = fmaxf(p.w, q.w);
            } else {
                c.x = fminf(p.x, q.x); c.y = fminf(p.y, q.y);
                c.z = fminf(p.z, q.z); c.w = fminf(p.w, q.w);
            }
            const floatx4 W0 = ld4(wk);
            const floatx4 W1 = ld4(wk + 256);
            acc0 += dot4(c, W0);
            acc1 += dot4(c, W1);
        }
    }

    // Reduce across the 32 lanes of this half-wave
    #pragma unroll
    for (int m = 16; m >= 1; m >>= 1) {
        acc0 += __shfl_xor(acc0, m, 64);
        acc1 += __shfl_xor(acc1, m, 64);
    }

    if (lane == 0) {
        float2 r; r.x = acc0; r.y = acc1;
        *reinterpret_cast<float2*>(out + b * 2) = r;
    }
}

extern "C" void kernel_launch(void* const* d_in, const int* in_sizes, int n_in,
                              void* d_out, int out_size, void* d_ws, size_t ws_size,
                              hipStream_t stream) {
    const int*   features  = (const int*)  d_in[0];
    const float* emb_mean  = (const float*)d_in[1];
    const float* emb_std   = (const float*)d_in[2];
    const float* W_nc      = (const float*)d_in[3];
    const float* W_cat     = (const float*)d_in[4];
    const float* log_alpha = (const float*)d_in[5];
    const float* noise     = (const float*)d_in[6];
    float*       out       = (float*)d_out;

    dim3 grid(BATCH / 16);  // 512 blocks
    dim3 block(512);        // 8 waves, 16 batch rows/block
    dsnas_kernel<<<grid, block, 0, stream>>>(features, emb_mean, emb_std,
                                             W_nc, W_cat, log_alpha, noise, out);
}